// Round 7
// baseline (110.478 us; speedup 1.0000x reference)
//
#include <hip/hip_runtime.h>
#include <hip/hip_bf16.h>

// Shapes are fixed by the problem definition.
#define B_   16
#define T_   4096
#define N_   512
#define D_   512
#define EPSF 1e-8f

typedef __attribute__((ext_vector_type(8))) short bf16x8; // 8 bf16 = 4 VGPRs
typedef __attribute__((ext_vector_type(4))) float f32x4;

#define MEMFENCE asm volatile("" ::: "memory")

// round-to-nearest-even f32 -> bf16, packed pair into one u32
__device__ __forceinline__ unsigned int pack2bf(float a, float b) {
  unsigned int ua = __float_as_uint(a);
  ua += 0x7fffu + ((ua >> 16) & 1u);
  unsigned int ub = __float_as_uint(b);
  ub += 0x7fffu + ((ub >> 16) & 1u);
  return (ua >> 16) | (ub & 0xffff0000u);
}

// async global->LDS, 16 B per lane
__device__ __forceinline__ void gload_lds16(const void* g, void* l) {
  __builtin_amdgcn_global_load_lds(
      (const __attribute__((address_space(1))) unsigned int*)g,
      (__attribute__((address_space(3))) unsigned int*)l, 16, 0, 0);
}

// ---------------------------------------------------------------------------
// Kernel A: distractor rows -> inv_nd (f32 norms) + bf16 copy (ydbf).
// ---------------------------------------------------------------------------
__global__ void rownorms_d(const float* __restrict__ yd,
                           float* __restrict__ inv_nd,
                           unsigned short* __restrict__ ydbf) {
  const int tid = threadIdx.x;
  const int g   = tid >> 4;
  const int t   = tid & 15;
  const int row = blockIdx.x * 16 + g;
  const float* dr = yd + (size_t)row * D_;
  unsigned short* ob = ydbf + (size_t)row * D_;

  float dd = 0.f;
#pragma unroll
  for (int k = 0; k < 8; ++k) {
    const int col = k * 64 + t * 4;
    float4 a = *(const float4*)(dr + col);
    dd += a.x * a.x + a.y * a.y + a.z * a.z + a.w * a.w;
    uint2 p;
    p.x = pack2bf(a.x, a.y);
    p.y = pack2bf(a.z, a.w);
    *(uint2*)(ob + col) = p;
  }
#pragma unroll
  for (int m = 1; m < 16; m <<= 1) dd += __shfl_xor(dd, m);
  if (t == 0) inv_nd[row] = 1.f / fmaxf(sqrtf(dd), EPSF);
}

// ---------------------------------------------------------------------------
// BK=32 staging/compute helpers.
// LDS rows are 64 B (32 bf16). Swizzle (involution, bits 5:4 ^= f(row)):
//   x(row) = (row ^ (row>>2)) & 3;  chunk' = chunk ^ x
// gives <=2-way bank aliasing on ds_read_b128 / gload writes (free, m136).
// Writer uses linear LDS dest + inverse-swizzled SOURCE (m173); reader
// applies the same XOR. Involution verified: swizzle touches only byte
// bits 5:4, row bits (>=6) unchanged.
// ---------------------------------------------------------------------------
__device__ __forceinline__ void stage_B32(unsigned char* buf,
                                          const unsigned short* __restrict__ Bb,
                                          int k0, int tid) {
#pragma unroll
  for (int j = 0; j < 4; ++j) {
    const int g   = j * 512 + tid;          // chunk 0..2047 (16 B each)
    const int row = g >> 2;                 // 4 chunks per 32-bf16 row
    const int x   = (row ^ (row >> 2)) & 3;
    const int sch = (g & 3) ^ x;            // inverse-swizzled source chunk
    gload_lds16(Bb + (size_t)row * D_ + k0 + (sch << 3), buf + (g << 4));
  }
}

__device__ __forceinline__ void loadA32(const float* __restrict__ Ab,
                                        const float* __restrict__ Tb,
                                        int k0, int tid,
                                        float4* va, float4* vb) {
#pragma unroll
  for (int j = 0; j < 2; ++j) {
    const int g   = j * 512 + tid;          // float4 0..1023
    const int row = g >> 3;                 // 8 float4 per 32-f32 row
    const int c4  = g & 7;
    const size_t off = (size_t)row * D_ + k0 + (c4 << 2);
    va[j] = *(const float4*)(Ab + off);
    vb[j] = *(const float4*)(Tb + off);
  }
}

__device__ __forceinline__ void writeA32(unsigned char* As,
                                         const float4* va, const float4* vb,
                                         int tid,
                                         float* cc, float* tt, float* ct) {
#pragma unroll
  for (int j = 0; j < 2; ++j) {
    const int g   = j * 512 + tid;
    const int row = g >> 3;
    const int c4  = g & 7;
    const int x   = (row ^ (row >> 2)) & 3;
    const int off = (row << 6) + ((((c4 >> 1) ^ x)) << 4) + ((c4 & 1) << 3);
    uint2 pa;
    pa.x = pack2bf(va[j].x, va[j].y);
    pa.y = pack2bf(va[j].z, va[j].w);
    *(uint2*)(As + off) = pa;
    cc[j] += va[j].x * va[j].x + va[j].y * va[j].y + va[j].z * va[j].z + va[j].w * va[j].w;
    tt[j] += vb[j].x * vb[j].x + vb[j].y * vb[j].y + vb[j].z * vb[j].z + vb[j].w * vb[j].w;
    ct[j] += va[j].x * vb[j].x + va[j].y * vb[j].y + va[j].z * vb[j].z + va[j].w * vb[j].w;
  }
}

__device__ __forceinline__ void compute32(const unsigned char* As,
                                          const unsigned char* Bs,
                                          int wm, int wn, int lane,
                                          f32x4 acc[4][8]) {
  const int kc = lane >> 4;
  bf16x8 af[4], bfr[8];
#pragma unroll
  for (int i = 0; i < 4; ++i) {
    const int ar = wm * 64 + i * 16 + (lane & 15);
    const int x  = (ar ^ (ar >> 2)) & 3;
    af[i] = *(const bf16x8*)(As + (ar << 6) + ((kc ^ x) << 4));
  }
#pragma unroll
  for (int n = 0; n < 8; ++n) {
    const int br = wn * 128 + n * 16 + (lane & 15);
    const int x  = (br ^ (br >> 2)) & 3;
    bfr[n] = *(const bf16x8*)(Bs + (br << 6) + ((kc ^ x) << 4));
  }
#pragma unroll
  for (int mi = 0; mi < 4; ++mi)
#pragma unroll
    for (int ni = 0; ni < 8; ++ni)
      acc[mi][ni] = __builtin_amdgcn_mfma_f32_16x16x32_bf16(
          af[mi], bfr[ni], acc[mi][ni], 0, 0, 0);
}

// ---------------------------------------------------------------------------
// Kernel B (r7): counted-vmcnt pipeline (T3+T4). One block per (mt,b).
// Per iter t: stage_B(t+2) [gload_lds, 4/thread]; loadA(t+2)->regs;
// writeA(t+1)->As[(t+1)%3]; s_waitcnt vmcnt(8) lgkmcnt(0); s_barrier;
// compute(t). vmcnt(8) is safe: B(t) has >=8 younger manual gloads
// (B(t+1),B(t+2)); in-order completion => B(t) landed. Buffer depths
// (Bs 4, As 3) make every WAR pair >=2 barriers apart. NEVER vmcnt(0)
// in the main loop (tail: 4, then 0).
// ---------------------------------------------------------------------------
__launch_bounds__(512, 2)
__global__ void fused_ct(const float* __restrict__ c,
                         const float* __restrict__ yt,
                         const unsigned short* __restrict__ ydbf,
                         const float* __restrict__ inv_nd,
                         float* __restrict__ rt,
                         float* __restrict__ S) {
  __shared__ __align__(16) unsigned char Bs[4][512 * 32 * 2];  // 4 x 32 KB
  __shared__ __align__(16) unsigned char As[3][128 * 32 * 2];  // 3 x 8 KB
  __shared__ float s_invc[128];
  __shared__ float s_invd[512];

  const int mt = blockIdx.x;
  const int b  = blockIdx.y;
  const int tid  = threadIdx.x;
  const int lane = tid & 63;
  const int w    = tid >> 6;
  const int wm   = w >> 2, wn = w & 3;   // 2 x 4 waves over 128 x 512 out

  const float* Ab = c  + ((size_t)b * T_ + (size_t)mt * 128) * D_;
  const float* Tb = yt + ((size_t)b * T_ + (size_t)mt * 128) * D_;
  const unsigned short* Bb = ydbf + (size_t)b * N_ * D_;

  float4 va0[2], vb0[2], va1[2], vb1[2];
  float cc[2] = {0.f, 0.f}, tt[2] = {0.f, 0.f}, ct[2] = {0.f, 0.f};

  // ---- prologue: tiles 0,1 ----
  stage_B32(Bs[0], Bb, 0, tid);
  stage_B32(Bs[1], Bb, 32, tid);
  loadA32(Ab, Tb, 0, tid, va0, vb0);
  loadA32(Ab, Tb, 32, tid, va1, vb1);
  s_invd[tid] = inv_nd[b * N_ + tid];
  writeA32(As[0], va0, vb0, tid, cc, tt, ct);   // tile 0 -> slot 0

  f32x4 acc[4][8] = {};
  int asC = 0, asW = 1;   // As slots: compute(t) reads t%3, writeA(t+1) -> (t+1)%3

  int t = 0;
#pragma unroll 1
  for (int tp = 0; tp < 7; ++tp) {
    // ---- even iter: loadA -> set0, writeA <- set1 ----
    stage_B32(Bs[(t + 2) & 3], Bb, (t + 2) * 32, tid);
    loadA32(Ab, Tb, (t + 2) * 32, tid, va0, vb0);
    writeA32(As[asW], va1, vb1, tid, cc, tt, ct);
    asm volatile("s_waitcnt vmcnt(8) lgkmcnt(0)" ::: "memory");
    __builtin_amdgcn_s_barrier();
    MEMFENCE;
    compute32(As[asC], Bs[t & 3], wm, wn, lane, acc);
    { int nW = 3 - asC - asW; asC = asW; asW = nW; }
    ++t;
    // ---- odd iter: loadA -> set1, writeA <- set0 ----
    stage_B32(Bs[(t + 2) & 3], Bb, (t + 2) * 32, tid);
    loadA32(Ab, Tb, (t + 2) * 32, tid, va1, vb1);
    writeA32(As[asW], va0, vb0, tid, cc, tt, ct);
    asm volatile("s_waitcnt vmcnt(8) lgkmcnt(0)" ::: "memory");
    __builtin_amdgcn_s_barrier();
    MEMFENCE;
    compute32(As[asC], Bs[t & 3], wm, wn, lane, acc);
    { int nW = 3 - asC - asW; asC = asW; asW = nW; }
    ++t;
  }
  // ---- t = 14: no more staging; writeA(15) <- set1 ----
  writeA32(As[asW], va1, vb1, tid, cc, tt, ct);
  asm volatile("s_waitcnt vmcnt(4) lgkmcnt(0)" ::: "memory");
  __builtin_amdgcn_s_barrier();
  MEMFENCE;
  compute32(As[asC], Bs[2], wm, wn, lane, acc);
  { int nW = 3 - asC - asW; asC = asW; asW = nW; }
  // ---- t = 15 ----
  asm volatile("s_waitcnt vmcnt(0) lgkmcnt(0)" ::: "memory");
  __builtin_amdgcn_s_barrier();
  MEMFENCE;
  compute32(As[asC], Bs[3], wm, wn, lane, acc);

  // ---- stats reduction: thread owns rows (tid>>3) and 64+(tid>>3),
  //      partials spread over c4 = tid&7 (8 contiguous lanes) ----
#pragma unroll
  for (int j = 0; j < 2; ++j) {
#pragma unroll
    for (int m = 1; m < 8; m <<= 1) {
      cc[j] += __shfl_xor(cc[j], m);
      tt[j] += __shfl_xor(tt[j], m);
      ct[j] += __shfl_xor(ct[j], m);
    }
    if ((tid & 7) == 0) {
      const int row = j * 64 + (tid >> 3);
      const float nc = fmaxf(sqrtf(cc[j]), EPSF);
      const float nt = fmaxf(sqrtf(tt[j]), EPSF);
      s_invc[row] = 1.f / nc;
      rt[b * T_ + mt * 128 + row] = ct[j] / (nt * nc);
    }
  }
  __syncthreads();

  // ---- epilogue: exp(acc*invc*invd) row-sum over all 512 cols ----
  float invd[8];
#pragma unroll
  for (int ni = 0; ni < 8; ++ni)
    invd[ni] = s_invd[wn * 128 + ni * 16 + (lane & 15)];

#pragma unroll
  for (int mi = 0; mi < 4; ++mi) {
    const int t0l = wm * 64 + mi * 16 + ((lane >> 4) << 2);  // local row
#pragma unroll
    for (int r = 0; r < 4; ++r) {
      const float invc = s_invc[t0l + r];
      float s = 0.f;
#pragma unroll
      for (int ni = 0; ni < 8; ++ni)
        s += __expf(acc[mi][ni][r] * invc * invd[ni]);
      s += __shfl_xor(s, 1);
      s += __shfl_xor(s, 2);
      s += __shfl_xor(s, 4);
      s += __shfl_xor(s, 8);
      if ((lane & 15) == 0)
        atomicAdd(&S[b * T_ + mt * 128 + t0l + r], s);
    }
  }
}

// ---------------------------------------------------------------------------
// Kernel C: loss = sum_{b,t} log(S + exp(r_t)) - r_t
// ---------------------------------------------------------------------------
__global__ void final_loss(const float* __restrict__ S,
                           const float* __restrict__ rt,
                           float* __restrict__ out) {
  const int tid = threadIdx.x;
  float sum = 0.f;
  for (int i = blockIdx.x * blockDim.x + tid; i < B_ * T_;
       i += gridDim.x * blockDim.x) {
    const float r = rt[i];
    sum += logf(S[i] + __expf(r)) - r;
  }
#pragma unroll
  for (int m = 32; m; m >>= 1) sum += __shfl_xor(sum, m);
  __shared__ float ws[4];
  if ((tid & 63) == 0) ws[tid >> 6] = sum;
  __syncthreads();
  if (tid == 0) atomicAdd(out, ws[0] + ws[1] + ws[2] + ws[3]);
}

// ---------------------------------------------------------------------------
extern "C" void kernel_launch(void* const* d_in, const int* in_sizes, int n_in,
                              void* d_out, int out_size, void* d_ws, size_t ws_size,
                              hipStream_t stream) {
  (void)in_sizes; (void)n_in; (void)out_size; (void)ws_size;
  const float* c  = (const float*)d_in[0];
  const float* yt = (const float*)d_in[1];
  const float* yd = (const float*)d_in[2];
  float* out = (float*)d_out;

  // ws layout: [ydbf: B*N*D u16][rt: B*T f][inv_nd: B*N f][S: B*T f]
  const size_t ydbf_n = (size_t)B_ * N_ * D_;   // 4.2M u16 = 8 MiB
  unsigned short* ydbf = (unsigned short*)d_ws;
  float* rt     = (float*)(ydbf + ydbf_n);      // B*T
  float* inv_nd = rt + B_ * T_;                 // B*N
  float* S      = inv_nd + B_ * N_;             // B*T

  hipMemsetAsync(S, 0, (size_t)B_ * T_ * sizeof(float), stream);
  hipMemsetAsync(out, 0, sizeof(float), stream);

  rownorms_d<<<B_ * N_ / 16, 256, 0, stream>>>(yd, inv_nd, ydbf);

  dim3 gF(T_ / 128, B_);   // (32, 16) = 512 blocks, 512 threads
  fused_ct<<<gF, 512, 0, stream>>>(c, yt, ydbf, inv_nd, rt, S);

  final_loss<<<64, 256, 0, stream>>>(S, rt, out);
}